// Round 2
// baseline (1796.530 us; speedup 1.0000x reference)
//
#include <hip/hip_runtime.h>
#include <hip/hip_bf16.h>

typedef __hip_bfloat16 bf16;

#define C_DIM 180
#define NHEAD 6
#define HD 30
#define HID 720
#define LN_EPS 1e-5f
#define IMG_TOK 16384   // 128*128 tokens per image

static __device__ __forceinline__ float bfr2f(unsigned short u) {
    union { unsigned int i; float f; } c; c.i = ((unsigned int)u) << 16; return c.f;
}
static __device__ __forceinline__ bf16 f2bf(float f) { return __float2bfloat16(f); }
static __device__ __forceinline__ float bf2f(bf16 v) { return __bfloat162float(v); }

// ---------------- LayerNorm: one wave (64 lanes) per row of 180 ----------------
__global__ __launch_bounds__(256) void ln_kernel(const float* __restrict__ x,
                                                 const float* __restrict__ w,
                                                 const float* __restrict__ b,
                                                 bf16* __restrict__ out, int M) {
    int wave = threadIdx.x >> 6;
    int lane = threadIdx.x & 63;
    long row = (long)blockIdx.x * 4 + wave;
    if (row >= M) return;
    const float* xr = x + row * C_DIM;
    float e0 = xr[lane];
    float e1 = xr[lane + 64];
    float e2 = (lane < C_DIM - 128) ? xr[lane + 128] : 0.f;
    float s  = e0 + e1 + e2;
    float ss = e0*e0 + e1*e1 + e2*e2;
    #pragma unroll
    for (int off = 32; off > 0; off >>= 1) {
        s  += __shfl_xor(s,  off);
        ss += __shfl_xor(ss, off);
    }
    float mean = s * (1.f / C_DIM);
    float var  = ss * (1.f / C_DIM) - mean * mean;
    float rs   = rsqrtf(var + LN_EPS);
    bf16* orow = out + row * C_DIM;
    orow[lane]      = f2bf((e0 - mean) * rs * w[lane]      + b[lane]);
    orow[lane + 64] = f2bf((e1 - mean) * rs * w[lane + 64] + b[lane + 64]);
    if (lane < C_DIM - 128)
        orow[lane + 128] = f2bf((e2 - mean) * rs * w[lane + 128] + b[lane + 128]);
}

// ---------------- Generic GEMM: C = act(A_bf16[M,K] @ B_f32[K,N] + bias) (+resid) ----------------
#define BM 64
#define BN 64
#define BK 32

__global__ __launch_bounds__(256) void gemm_kernel(
    const bf16* __restrict__ A, const float* __restrict__ B,
    const float* __restrict__ bias, const float* __restrict__ resid,
    bf16* __restrict__ outb, float* __restrict__ outf,
    int M, int N, int K, int do_gelu)
{
    __shared__ __align__(16) float As[BK][BM];
    __shared__ __align__(16) float Bs[BK][BN];
    int tid = threadIdx.x;
    int tx = tid & 15, ty = tid >> 4;
    long m0 = (long)blockIdx.y * BM;
    int  n0 = blockIdx.x * BN;

    float acc[4][4] = {};

    int ktiles = (K + BK - 1) / BK;
    for (int kt = 0; kt < ktiles; ++kt) {
        int k0 = kt * BK;
        // stage A tile: 64 rows x 32 k  (thread: row=tid>>2, k-seg=tid&3, 8 elems)
        {
            int r  = tid >> 2;
            int s4 = tid & 3;
            int kb = k0 + s4 * 8;
            const bf16* ap = A + (m0 + r) * (long)K + kb;
            float av[8];
            if (kb + 8 <= K) {
                ushort4 u0 = *(const ushort4*)(ap);
                ushort4 u1 = *(const ushort4*)(ap + 4);
                av[0] = bfr2f(u0.x); av[1] = bfr2f(u0.y); av[2] = bfr2f(u0.z); av[3] = bfr2f(u0.w);
                av[4] = bfr2f(u1.x); av[5] = bfr2f(u1.y); av[6] = bfr2f(u1.z); av[7] = bfr2f(u1.w);
            } else {
                #pragma unroll
                for (int j = 0; j < 8; ++j) av[j] = (kb + j < K) ? bf2f(ap[j]) : 0.f;
            }
            #pragma unroll
            for (int j = 0; j < 8; ++j) As[s4 * 8 + j][r] = av[j];
        }
        // stage B tile: 32 k x 64 n  (thread: k=tid>>3, n-seg=tid&7, 8 elems)
        {
            int kr = tid >> 3;
            int s8 = tid & 7;
            int krow = k0 + kr;
            int nb = n0 + s8 * 8;
            const float* bp = B + (long)krow * N + nb;
            float bv[8];
            if (krow < K && nb + 8 <= N) {
                float4 b0 = *(const float4*)(bp);
                float4 b1 = *(const float4*)(bp + 4);
                bv[0] = b0.x; bv[1] = b0.y; bv[2] = b0.z; bv[3] = b0.w;
                bv[4] = b1.x; bv[5] = b1.y; bv[6] = b1.z; bv[7] = b1.w;
            } else {
                #pragma unroll
                for (int j = 0; j < 8; ++j)
                    bv[j] = (krow < K && nb + j < N) ? bp[j] : 0.f;
            }
            #pragma unroll
            for (int j = 0; j < 8; ++j) Bs[kr][s8 * 8 + j] = bv[j];
        }
        __syncthreads();
        #pragma unroll
        for (int k = 0; k < BK; ++k) {
            float4 a = *(const float4*)(&As[k][ty * 4]);
            float4 b = *(const float4*)(&Bs[k][tx * 4]);
            float a_[4] = {a.x, a.y, a.z, a.w};
            float b_[4] = {b.x, b.y, b.z, b.w};
            #pragma unroll
            for (int i = 0; i < 4; ++i)
                #pragma unroll
                for (int j = 0; j < 4; ++j)
                    acc[i][j] = fmaf(a_[i], b_[j], acc[i][j]);
        }
        __syncthreads();
    }

    #pragma unroll
    for (int i = 0; i < 4; ++i) {
        long row = m0 + ty * 4 + i;
        #pragma unroll
        for (int j = 0; j < 4; ++j) {
            int col = n0 + tx * 4 + j;
            if (col < N) {
                float v = acc[i][j] + bias[col];
                if (do_gelu) v = 0.5f * v * (1.f + erff(v * 0.70710678118f));
                if (resid) v += resid[row * N + col];
                if (outf) outf[row * N + col] = v;
                else      outb[row * N + col] = f2bf(v);
            }
        }
    }
}

// ---------------- Window attention: one wave per (window, head) ----------------
// qkv/o point at the CHUNK base; blockIdx.y = window index within chunk.
__global__ __launch_bounds__(64) void attn_kernel(
    const bf16* __restrict__ qkv, const float* __restrict__ table,
    bf16* __restrict__ o)
{
    __shared__ __align__(16) float Ks[64][HD];
    __shared__ __align__(16) float Vs[64][HD];
    __shared__ float Bt[225];
    int h = blockIdx.x;          // head 0..5
    int w = blockIdx.y;          // window within chunk
    int lane = threadIdx.x;      // 0..63 = query row
    int b   = w >> 8;            // image within chunk (256 windows per image)
    int rem = w & 255;
    int wi = rem >> 4, wj = rem & 15;
    int r = lane >> 3, c = lane & 7;
    long grow = (long)b * IMG_TOK + (long)(wi * 8 + r) * 128 + (wj * 8 + c);

    const bf16* qp = qkv + grow * 540 + h * HD;
    const float scale = 0.18257418583505536f;   // 30^-0.5
    float q[HD];
    #pragma unroll
    for (int d = 0; d < HD; ++d) {
        q[d] = bf2f(qp[d]) * scale;
        Ks[lane][d] = bf2f(qp[180 + d]);
        Vs[lane][d] = bf2f(qp[360 + d]);
    }
    for (int i = lane; i < 225; i += 64) Bt[i] = table[i * NHEAD + h];
    __syncthreads();

    float m = -1e30f, l = 0.f;
    float oa[HD];
    #pragma unroll
    for (int d = 0; d < HD; ++d) oa[d] = 0.f;

    int ri = r, ci = c;
    for (int j = 0; j < 64; ++j) {
        int rj = j >> 3, cj = j & 7;
        float s = Bt[(ri - rj + 7) * 15 + (ci - cj + 7)];
        #pragma unroll
        for (int d = 0; d < HD; ++d) s = fmaf(q[d], Ks[j][d], s);
        float mn   = fmaxf(m, s);
        float corr = __expf(m - mn);
        float p    = __expf(s - mn);
        l = l * corr + p;
        #pragma unroll
        for (int d = 0; d < HD; ++d) oa[d] = fmaf(oa[d], corr, p * Vs[j][d]);
        m = mn;
    }
    float inv = 1.f / l;
    bf16* op = o + grow * C_DIM + h * HD;
    #pragma unroll
    for (int d = 0; d < HD; ++d) op[d] = f2bf(oa[d] * inv);
}

// ---------------- host launch ----------------
extern "C" void kernel_launch(void* const* d_in, const int* in_sizes, int n_in,
                              void* d_out, int out_size, void* d_ws, size_t ws_size,
                              hipStream_t stream) {
    const float* x    = (const float*)d_in[0];
    const float* n1w  = (const float*)d_in[1];
    const float* n1b  = (const float*)d_in[2];
    const float* qkvw = (const float*)d_in[3];
    const float* qkvb = (const float*)d_in[4];
    const float* tbl  = (const float*)d_in[5];
    const float* pw   = (const float*)d_in[6];
    const float* pb   = (const float*)d_in[7];
    const float* n2w  = (const float*)d_in[8];
    const float* n2b  = (const float*)d_in[9];
    const float* f1w  = (const float*)d_in[10];
    const float* f1b  = (const float*)d_in[11];
    const float* f2w  = (const float*)d_in[12];
    const float* f2b  = (const float*)d_in[13];

    // Per-image scratch (aliased across pipeline stages):
    //   R1: qkv bf16 [Mc,540]  then  h bf16 [Mc,720]   (qkv dead after attn)
    //   R2: xn bf16 [Mc,180] -> obuf -> x2n             (sequential lifetimes)
    //   R3: x1 f32 [Mc,180]                             (live proj..fc2)
    // Choose images-per-chunk g from ws_size (ws_size is fixed -> deterministic).
    auto al = [](size_t b) { return (b + 255) & ~(size_t)255; };
    size_t r1_per = al((size_t)IMG_TOK * HID * 2);
    size_t r2_per = al((size_t)IMG_TOK * C_DIM * 2);
    size_t r3_per = al((size_t)IMG_TOK * C_DIM * 4);
    size_t per_img = r1_per + r2_per + r3_per;
    int g = 8;
    while (g > 1 && per_img * (size_t)g > ws_size) g >>= 1;
    int nchunks = 8 / g;
    long Mc = (long)IMG_TOK * g;

    char* base = (char*)d_ws;
    bf16*  R1 = (bf16*)base;
    bf16*  R2 = (bf16*)(base + r1_per * g);
    float* R3 = (float*)(base + (r1_per + r2_per) * g);

    for (int ci = 0; ci < nchunks; ++ci) {
        const float* xc   = x + (size_t)ci * Mc * C_DIM;
        float*       outc = (float*)d_out + (size_t)ci * Mc * C_DIM;

        // 1. LN1 -> R2 (xn)
        ln_kernel<<<Mc / 4, 256, 0, stream>>>(xc, n1w, n1b, R2, (int)Mc);
        // 2. QKV: [Mc,180] @ [180,540] -> R1 (qkv)
        gemm_kernel<<<dim3(9, Mc / BM), 256, 0, stream>>>(R2, qkvw, qkvb, nullptr,
                                                          R1, nullptr, (int)Mc, 540, C_DIM, 0);
        // 3. window attention: R1(qkv) -> R2 (o)
        attn_kernel<<<dim3(NHEAD, 256 * g), 64, 0, stream>>>(R1, tbl, R2);
        // 4. proj + residual(x) -> R3 (x1, f32)
        gemm_kernel<<<dim3(3, Mc / BM), 256, 0, stream>>>(R2, pw, pb, xc,
                                                          nullptr, R3, (int)Mc, C_DIM, C_DIM, 0);
        // 5. LN2 -> R2 (x2n)
        ln_kernel<<<Mc / 4, 256, 0, stream>>>(R3, n2w, n2b, R2, (int)Mc);
        // 6. FC1 + GELU: [Mc,180] @ [180,720] -> R1 (h)
        gemm_kernel<<<dim3(12, Mc / BM), 256, 0, stream>>>(R2, f1w, f1b, nullptr,
                                                           R1, nullptr, (int)Mc, HID, C_DIM, 1);
        // 7. FC2 + residual(x1) -> out (f32)
        gemm_kernel<<<dim3(3, Mc / BM), 256, 0, stream>>>(R1, f2w, f2b, R3,
                                                          nullptr, outc, (int)Mc, C_DIM, HID, 0);
    }
}

// Round 3
// 766.835 us; speedup vs baseline: 2.3428x; 2.3428x over previous
//
#include <hip/hip_runtime.h>
#include <hip/hip_bf16.h>

typedef __hip_bfloat16 bf16;
typedef __attribute__((ext_vector_type(8))) short short8;
typedef __attribute__((ext_vector_type(4))) float f32x4;

#define C_DIM 180
#define CPAD  192
#define NHEAD 6
#define HD    30
#define HID   720
#define HPAD  768
#define LN_EPS 1e-5f
#define IMG_TOK 16384   // 128*128 tokens per image

static __device__ __forceinline__ bf16 f2bf(float f) { return __float2bfloat16(f); }
static __device__ __forceinline__ float bf2f(bf16 v) { return __bfloat162float(v); }

// ---------------- weight prep: f32 [K][N] -> bf16 transposed padded [Npad][Kpad] ----------------
__global__ __launch_bounds__(256) void prep_w(const float* __restrict__ w, bf16* __restrict__ bt,
                                              int K, int N, int Kpad, int Npad) {
    int idx = blockIdx.x * 256 + threadIdx.x;
    if (idx >= Kpad * Npad) return;
    int k = idx % Kpad, n = idx / Kpad;
    float v = (k < K && n < N) ? w[(long)k * N + n] : 0.f;
    bt[idx] = f2bf(v);
}

// ---------------- LayerNorm: one wave per row of 180; writes stride-192, zero-padded ----------------
__global__ __launch_bounds__(256) void ln_kernel(const float* __restrict__ x,
                                                 const float* __restrict__ w,
                                                 const float* __restrict__ b,
                                                 bf16* __restrict__ out, int M) {
    int wave = threadIdx.x >> 6;
    int lane = threadIdx.x & 63;
    long row = (long)blockIdx.x * 4 + wave;
    if (row >= M) return;
    const float* xr = x + row * C_DIM;
    float e0 = xr[lane];
    float e1 = xr[lane + 64];
    float e2 = (lane < C_DIM - 128) ? xr[lane + 128] : 0.f;
    float s  = e0 + e1 + e2;
    float ss = e0*e0 + e1*e1 + e2*e2;
    #pragma unroll
    for (int off = 32; off > 0; off >>= 1) {
        s  += __shfl_xor(s,  off);
        ss += __shfl_xor(ss, off);
    }
    float mean = s * (1.f / C_DIM);
    float var  = ss * (1.f / C_DIM) - mean * mean;
    float rs   = rsqrtf(var + LN_EPS);
    bf16* orow = out + row * CPAD;
    orow[lane]      = f2bf((e0 - mean) * rs * w[lane]      + b[lane]);
    orow[lane + 64] = f2bf((e1 - mean) * rs * w[lane + 64] + b[lane + 64]);
    if (lane < C_DIM - 128)
        orow[lane + 128] = f2bf((e2 - mean) * rs * w[lane + 128] + b[lane + 128]);
    if (lane < CPAD - C_DIM)
        orow[C_DIM + lane] = f2bf(0.f);
}

// ---------------- MFMA GEMM: out = act(A_bf16[M,lda<-Kpad] @ Bt^T + bias) (+resid) ----------------
// Tile 128x64, BK=64, 4 waves (2x2), mfma_f32_16x16x32_bf16.
// LDS layout: row-major [rows][64] bf16, 16B chunk c of row r holds global chunk (c ^ (r&7)).
#define GLL16(gp, lp) \
    __builtin_amdgcn_global_load_lds((const __attribute__((address_space(1))) unsigned int*)(gp), \
                                     (__attribute__((address_space(3))) unsigned int*)(lp), 16, 0, 0)

template<int DO_GELU, int OUT_F32>
__global__ __launch_bounds__(256) void mfma_gemm(
    const bf16* __restrict__ A, int lda,
    const bf16* __restrict__ Bt,            // [Npad][Kpad]
    const float* __restrict__ bias, int N,
    const float* __restrict__ resid, int nres,
    void* __restrict__ out, int ldo, int nstore,
    int Kpad)
{
    __shared__ short As[128 * 64];
    __shared__ short Bs[64 * 64];
    int tid  = threadIdx.x;
    int lane = tid & 63;
    int wave = tid >> 6;
    int wm = wave >> 1, wn = wave & 1;
    long m0 = (long)blockIdx.y * 128;
    int  n0 = blockIdx.x * 64;

    f32x4 acc[4][2] = {};

    int nkt = Kpad >> 6;
    for (int kt = 0; kt < nkt; ++kt) {
        int k0 = kt << 6;
        #pragma unroll
        for (int i = 0; i < 4; ++i) {      // A tile: 128 rows x 8 chunks
            int f = i * 256 + tid;
            int r = f >> 3, c = f & 7;
            const bf16* gp = A + (m0 + r) * (long)lda + k0 + ((c ^ (r & 7)) << 3);
            GLL16(gp, &As[(i * 256 + (wave << 6)) * 8]);
        }
        #pragma unroll
        for (int i = 0; i < 2; ++i) {      // B tile: 64 rows x 8 chunks
            int f = i * 256 + tid;
            int r = f >> 3, c = f & 7;
            const bf16* gp = Bt + (n0 + r) * (long)Kpad + k0 + ((c ^ (r & 7)) << 3);
            GLL16(gp, &Bs[(i * 256 + (wave << 6)) * 8]);
        }
        __syncthreads();
        #pragma unroll
        for (int ks = 0; ks < 2; ++ks) {
            short8 af[4], bfr[2];
            #pragma unroll
            for (int fi = 0; fi < 4; ++fi) {
                int r  = wm * 64 + fi * 16 + (lane & 15);
                int ch = ks * 4 + (lane >> 4);
                af[fi] = *(const short8*)&As[r * 64 + ((ch ^ (r & 7)) << 3)];
            }
            #pragma unroll
            for (int fj = 0; fj < 2; ++fj) {
                int r  = wn * 32 + fj * 16 + (lane & 15);
                int ch = ks * 4 + (lane >> 4);
                bfr[fj] = *(const short8*)&Bs[r * 64 + ((ch ^ (r & 7)) << 3)];
            }
            #pragma unroll
            for (int fi = 0; fi < 4; ++fi)
                #pragma unroll
                for (int fj = 0; fj < 2; ++fj)
                    acc[fi][fj] = __builtin_amdgcn_mfma_f32_16x16x32_bf16(af[fi], bfr[fj], acc[fi][fj], 0, 0, 0);
        }
        __syncthreads();
    }

    #pragma unroll
    for (int fi = 0; fi < 4; ++fi) {
        #pragma unroll
        for (int fj = 0; fj < 2; ++fj) {
            int col = n0 + wn * 32 + fj * 16 + (lane & 15);
            if (col >= nstore) continue;
            float bv = (col < N) ? bias[col] : 0.f;
            #pragma unroll
            for (int rg = 0; rg < 4; ++rg) {
                long row = m0 + wm * 64 + fi * 16 + (lane >> 4) * 4 + rg;
                float v = 0.f;
                if (col < N) {
                    v = acc[fi][fj][rg] + bv;
                    if (DO_GELU) v = 0.5f * v * (1.f + erff(v * 0.70710678118f));
                    if (resid) v += resid[row * (long)nres + col];
                }
                if (OUT_F32) ((float*)out)[row * (long)ldo + col] = v;
                else         ((bf16*)out)[row * (long)ldo + col] = f2bf(v);
            }
        }
    }
}

// ---------------- Window attention: one wave per (window, head) ----------------
__global__ __launch_bounds__(64) void attn_kernel(
    const bf16* __restrict__ qkv, const float* __restrict__ table,
    bf16* __restrict__ o)
{
    __shared__ __align__(16) float Ks[64][HD];
    __shared__ __align__(16) float Vs[64][HD];
    __shared__ float Bt[225];
    int h = blockIdx.x;          // head 0..5
    int w = blockIdx.y;          // window within chunk
    int lane = threadIdx.x;      // 0..63 = query row
    int b   = w >> 8;
    int rem = w & 255;
    int wi = rem >> 4, wj = rem & 15;
    int r = lane >> 3, c = lane & 7;
    long grow = (long)b * IMG_TOK + (long)(wi * 8 + r) * 128 + (wj * 8 + c);

    const bf16* qp = qkv + grow * 540 + h * HD;
    const float scale = 0.18257418583505536f;   // 30^-0.5
    float q[HD];
    #pragma unroll
    for (int d = 0; d < HD; ++d) {
        q[d] = bf2f(qp[d]) * scale;
        Ks[lane][d] = bf2f(qp[180 + d]);
        Vs[lane][d] = bf2f(qp[360 + d]);
    }
    for (int i = lane; i < 225; i += 64) Bt[i] = table[i * NHEAD + h];
    __syncthreads();

    float m = -1e30f, l = 0.f;
    float oa[HD];
    #pragma unroll
    for (int d = 0; d < HD; ++d) oa[d] = 0.f;

    int ri = r, ci = c;
    for (int j = 0; j < 64; ++j) {
        int rj = j >> 3, cj = j & 7;
        float s = Bt[(ri - rj + 7) * 15 + (ci - cj + 7)];
        #pragma unroll
        for (int d = 0; d < HD; ++d) s = fmaf(q[d], Ks[j][d], s);
        float mn   = fmaxf(m, s);
        float corr = __expf(m - mn);
        float p    = __expf(s - mn);
        l = l * corr + p;
        #pragma unroll
        for (int d = 0; d < HD; ++d) oa[d] = fmaf(oa[d], corr, p * Vs[j][d]);
        m = mn;
    }
    float inv = 1.f / l;
    bf16* op = o + grow * CPAD + h * HD;
    #pragma unroll
    for (int d = 0; d < HD; ++d) op[d] = f2bf(oa[d] * inv);
    if (h == 0) {
        #pragma unroll
        for (int j = 0; j < CPAD - C_DIM; ++j) o[grow * CPAD + C_DIM + j] = f2bf(0.f);
    }
}

// ---------------- host launch ----------------
extern "C" void kernel_launch(void* const* d_in, const int* in_sizes, int n_in,
                              void* d_out, int out_size, void* d_ws, size_t ws_size,
                              hipStream_t stream) {
    const float* x    = (const float*)d_in[0];
    const float* n1w  = (const float*)d_in[1];
    const float* n1b  = (const float*)d_in[2];
    const float* qkvw = (const float*)d_in[3];
    const float* qkvb = (const float*)d_in[4];
    const float* tbl  = (const float*)d_in[5];
    const float* pw   = (const float*)d_in[6];
    const float* pb   = (const float*)d_in[7];
    const float* n2w  = (const float*)d_in[8];
    const float* n2b  = (const float*)d_in[9];
    const float* f1w  = (const float*)d_in[10];
    const float* f1b  = (const float*)d_in[11];
    const float* f2w  = (const float*)d_in[12];
    const float* f2b  = (const float*)d_in[13];

    auto al = [](size_t b) { return (b + 255) & ~(size_t)255; };
    char* base = (char*)d_ws;
    size_t off = 0;
    auto alloc = [&](size_t bytes) -> char* { char* p = base + off; off += al(bytes); return p; };

    // bf16 transposed padded weights (prepped every call; deterministic)
    bf16* wq  = (bf16*)alloc((size_t)576 * 192 * 2);
    bf16* wp  = (bf16*)alloc((size_t)192 * 192 * 2);
    bf16* wf1 = (bf16*)alloc((size_t)768 * 192 * 2);
    bf16* wf2 = (bf16*)alloc((size_t)192 * 768 * 2);
    size_t woff = off;

    // per-image chunk scratch
    size_t r1_per = al((size_t)IMG_TOK * HPAD * 2);   // qkv[540] then h[768]
    size_t r2_per = al((size_t)IMG_TOK * CPAD * 2);   // xn -> o -> x2n
    size_t r3_per = al((size_t)IMG_TOK * C_DIM * 4);  // x1 f32
    size_t per_img = r1_per + r2_per + r3_per;
    int g = 8;
    while (g > 1 && woff + per_img * (size_t)g > ws_size) g >>= 1;
    int nchunks = 8 / g;
    long Mc = (long)IMG_TOK * g;

    bf16*  R1 = (bf16*)(base + woff);
    bf16*  R2 = (bf16*)(base + woff + r1_per * g);
    float* R3 = (float*)(base + woff + (r1_per + r2_per) * g);

    prep_w<<<(576 * 192 + 255) / 256, 256, 0, stream>>>(qkvw, wq, 180, 540, 192, 576);
    prep_w<<<(192 * 192 + 255) / 256, 256, 0, stream>>>(pw, wp, 180, 180, 192, 192);
    prep_w<<<(768 * 192 + 255) / 256, 256, 0, stream>>>(f1w, wf1, 180, 720, 192, 768);
    prep_w<<<(192 * 768 + 255) / 256, 256, 0, stream>>>(f2w, wf2, 720, 180, 768, 192);

    for (int ci = 0; ci < nchunks; ++ci) {
        const float* xc   = x + (size_t)ci * Mc * C_DIM;
        float*       outc = (float*)d_out + (size_t)ci * Mc * C_DIM;

        // 1. LN1 -> R2 (xn, stride 192, zero-padded)
        ln_kernel<<<Mc / 4, 256, 0, stream>>>(xc, n1w, n1b, R2, (int)Mc);
        // 2. QKV -> R1 [Mc,540] bf16
        mfma_gemm<0, 0><<<dim3(9, Mc / 128), 256, 0, stream>>>(
            R2, CPAD, wq, qkvb, 540, nullptr, 0, R1, 540, 540, CPAD);
        // 3. window attention -> R2 (o, stride 192, zero-padded)
        attn_kernel<<<dim3(NHEAD, 256 * g), 64, 0, stream>>>(R1, tbl, R2);
        // 4. proj + residual(x) -> R3 (x1, f32, stride 180)
        mfma_gemm<0, 1><<<dim3(3, Mc / 128), 256, 0, stream>>>(
            R2, CPAD, wp, pb, 180, xc, 180, R3, 180, 180, CPAD);
        // 5. LN2 -> R2 (x2n)
        ln_kernel<<<Mc / 4, 256, 0, stream>>>(R3, n2w, n2b, R2, (int)Mc);
        // 6. FC1 + GELU -> R1 (h, stride 768, zero-padded)
        mfma_gemm<1, 0><<<dim3(12, Mc / 128), 256, 0, stream>>>(
            R2, CPAD, wf1, f1b, 720, nullptr, 0, R1, HPAD, HPAD, CPAD);
        // 7. FC2 + residual(x1) -> out (f32)
        mfma_gemm<0, 1><<<dim3(3, Mc / 128), 256, 0, stream>>>(
            R1, HPAD, wf2, f2b, 180, R3, 180, outc, 180, 180, HPAD);
    }
}

// Round 4
// 625.056 us; speedup vs baseline: 2.8742x; 1.2268x over previous
//
#include <hip/hip_runtime.h>
#include <hip/hip_bf16.h>

typedef __hip_bfloat16 bf16;
typedef __attribute__((ext_vector_type(8))) short short8;
typedef __attribute__((ext_vector_type(4))) short short4v;
typedef __attribute__((ext_vector_type(4))) float f32x4;

#define C_DIM 180
#define CPAD  192
#define NHEAD 6
#define HD    30
#define HID   720
#define HPAD  768
#define LN_EPS 1e-5f
#define IMG_TOK 16384   // 128*128 tokens per image
#define QSCALE 0.18257418583505536f

static __device__ __forceinline__ bf16 f2bf(float f) { return __float2bfloat16(f); }
static __device__ __forceinline__ float bf2f(bf16 v) { return __bfloat162float(v); }
static __device__ __forceinline__ short bfbits(float f) {
    bf16 b = __float2bfloat16(f); return *reinterpret_cast<short*>(&b);
}

// ---------------- weight prep: f32 [K][N] -> bf16 transposed padded [Npad][Kpad] ----------------
__global__ __launch_bounds__(256) void prep_w(const float* __restrict__ w, bf16* __restrict__ bt,
                                              int K, int N, int Kpad, int Npad) {
    int idx = blockIdx.x * 256 + threadIdx.x;
    if (idx >= Kpad * Npad) return;
    int k = idx % Kpad, n = idx / Kpad;
    float v = (k < K && n < N) ? w[(long)k * N + n] : 0.f;
    bt[idx] = f2bf(v);
}

// ---------------- bias prep: tbl[225][6] -> bias_frag[h][fi][fj][lane] f32x4 ----------------
__global__ __launch_bounds__(256) void prep_bias(const float* __restrict__ tbl,
                                                 float* __restrict__ bias_frag) {
    int idx = blockIdx.x * 256 + threadIdx.x;   // 6*4*4*64 = 6144
    if (idx >= 6144) return;
    int lane = idx & 63;
    int fj = (idx >> 6) & 3;
    int fi = (idx >> 8) & 3;
    int h  = idx >> 10;
    int g = lane >> 4, l15 = lane & 15;
    int kk = fj * 16 + l15;
    int rk = kk >> 3, ck = kk & 7;
    #pragma unroll
    for (int r = 0; r < 4; ++r) {
        int q = fi * 16 + g * 4 + r;
        int rq = q >> 3, cq = q & 7;
        int bidx = (rq - rk + 7) * 15 + (cq - ck + 7);
        bias_frag[idx * 4 + r] = tbl[bidx * NHEAD + h];
    }
}

// ---------------- LayerNorm: one wave per row of 180; writes stride-192, zero-padded ----------------
__global__ __launch_bounds__(256) void ln_kernel(const float* __restrict__ x,
                                                 const float* __restrict__ w,
                                                 const float* __restrict__ b,
                                                 bf16* __restrict__ out, int M) {
    int wave = threadIdx.x >> 6;
    int lane = threadIdx.x & 63;
    long row = (long)blockIdx.x * 4 + wave;
    if (row >= M) return;
    const float* xr = x + row * C_DIM;
    float e0 = xr[lane];
    float e1 = xr[lane + 64];
    float e2 = (lane < C_DIM - 128) ? xr[lane + 128] : 0.f;
    float s  = e0 + e1 + e2;
    float ss = e0*e0 + e1*e1 + e2*e2;
    #pragma unroll
    for (int off = 32; off > 0; off >>= 1) {
        s  += __shfl_xor(s,  off);
        ss += __shfl_xor(ss, off);
    }
    float mean = s * (1.f / C_DIM);
    float var  = ss * (1.f / C_DIM) - mean * mean;
    float rs   = rsqrtf(var + LN_EPS);
    bf16* orow = out + row * CPAD;
    orow[lane]      = f2bf((e0 - mean) * rs * w[lane]      + b[lane]);
    orow[lane + 64] = f2bf((e1 - mean) * rs * w[lane + 64] + b[lane + 64]);
    if (lane < C_DIM - 128)
        orow[lane + 128] = f2bf((e2 - mean) * rs * w[lane + 128] + b[lane + 128]);
    if (lane < CPAD - C_DIM)
        orow[C_DIM + lane] = f2bf(0.f);
}

// ---------------- MFMA GEMM ----------------
// OUT_MODE: 0 = bf16 linear, 1 = f32 linear (+resid), 2 = QKV split [Mc][6][32]x3
#define GLL16(gp, lp) \
    __builtin_amdgcn_global_load_lds((const __attribute__((address_space(1))) unsigned int*)(gp), \
                                     (__attribute__((address_space(3))) unsigned int*)(lp), 16, 0, 0)

template<int DO_GELU, int OUT_MODE>
__global__ __launch_bounds__(256) void mfma_gemm(
    const bf16* __restrict__ A, int lda,
    const bf16* __restrict__ Bt,            // [Npad][Kpad]
    const float* __restrict__ bias, int N,
    const float* __restrict__ resid, int nres,
    void* __restrict__ out, int ldo, int nstore,
    int Kpad, long matStride)
{
    __shared__ short As[128 * 64];
    __shared__ short Bs[64 * 64];
    int tid  = threadIdx.x;
    int lane = tid & 63;
    int wave = tid >> 6;
    int wm = wave >> 1, wn = wave & 1;
    long m0 = (long)blockIdx.y * 128;
    int  n0 = blockIdx.x * 64;

    f32x4 acc[4][2] = {};

    int nkt = Kpad >> 6;
    for (int kt = 0; kt < nkt; ++kt) {
        int k0 = kt << 6;
        #pragma unroll
        for (int i = 0; i < 4; ++i) {      // A tile: 128 rows x 8 chunks
            int f = i * 256 + tid;
            int r = f >> 3, c = f & 7;
            const bf16* gp = A + (m0 + r) * (long)lda + k0 + ((c ^ (r & 7)) << 3);
            GLL16(gp, &As[(i * 256 + (wave << 6)) * 8]);
        }
        #pragma unroll
        for (int i = 0; i < 2; ++i) {      // B tile: 64 rows x 8 chunks
            int f = i * 256 + tid;
            int r = f >> 3, c = f & 7;
            const bf16* gp = Bt + (n0 + r) * (long)Kpad + k0 + ((c ^ (r & 7)) << 3);
            GLL16(gp, &Bs[(i * 256 + (wave << 6)) * 8]);
        }
        __syncthreads();
        #pragma unroll
        for (int ks = 0; ks < 2; ++ks) {
            short8 af[4], bfr[2];
            #pragma unroll
            for (int fi = 0; fi < 4; ++fi) {
                int r  = wm * 64 + fi * 16 + (lane & 15);
                int ch = ks * 4 + (lane >> 4);
                af[fi] = *(const short8*)&As[r * 64 + ((ch ^ (r & 7)) << 3)];
            }
            #pragma unroll
            for (int fj = 0; fj < 2; ++fj) {
                int r  = wn * 32 + fj * 16 + (lane & 15);
                int ch = ks * 4 + (lane >> 4);
                bfr[fj] = *(const short8*)&Bs[r * 64 + ((ch ^ (r & 7)) << 3)];
            }
            #pragma unroll
            for (int fi = 0; fi < 4; ++fi)
                #pragma unroll
                for (int fj = 0; fj < 2; ++fj)
                    acc[fi][fj] = __builtin_amdgcn_mfma_f32_16x16x32_bf16(af[fi], bfr[fj], acc[fi][fj], 0, 0, 0);
        }
        __syncthreads();
    }

    #pragma unroll
    for (int fi = 0; fi < 4; ++fi) {
        #pragma unroll
        for (int fj = 0; fj < 2; ++fj) {
            int col = n0 + wn * 32 + fj * 16 + (lane & 15);
            if (col >= nstore) continue;
            float bv = bias[col];
            #pragma unroll
            for (int rg = 0; rg < 4; ++rg) {
                long row = m0 + wm * 64 + fi * 16 + (lane >> 4) * 4 + rg;
                float v = acc[fi][fj][rg] + bv;
                if (DO_GELU) v = 0.5f * v * (1.f + erff(v * 0.70710678118f));
                if (OUT_MODE == 1) {
                    if (resid) v += resid[row * (long)nres + col];
                    ((float*)out)[row * (long)ldo + col] = v;
                } else if (OUT_MODE == 0) {
                    ((bf16*)out)[row * (long)ldo + col] = f2bf(v);
                } else {
                    // QKV split: col -> (mat, head, d)
                    int mat = (col >= 360) ? 2 : (col >= 180 ? 1 : 0);
                    int rem = col - mat * 180;
                    int hh = rem / 30;
                    int dd = rem - hh * 30;
                    if (mat == 0) v *= QSCALE;
                    ((bf16*)out)[mat * matStride + row * 192 + hh * 32 + dd] = f2bf(v);
                }
            }
        }
    }
}

// ---------------- MFMA window attention: block = 1 window x 6 heads (384 thr) ----------------
__global__ __launch_bounds__(384, 3) void attn_mfma(
    const bf16* __restrict__ Qg, const bf16* __restrict__ Kg, const bf16* __restrict__ Vg,
    const float* __restrict__ bias_frag,    // [6][4][4][64] f32x4
    bf16* __restrict__ o)
{
    __shared__ __align__(16) short lds[6 * 4096];   // 8KB per wave
    int tid  = threadIdx.x;
    int wave = tid >> 6;            // = head
    int lane = tid & 63;
    int h = wave;
    int w = blockIdx.x;
    int b = w >> 8, rem = w & 255;
    int wi = rem >> 4, wj = rem & 15;
    long base = (long)b * IMG_TOK + wi * 8 * 128 + wj * 8;
    int g = lane >> 4, l15 = lane & 15;

    short* Vt = &lds[wave * 4096];          // [32][64] bf16, chunk-swizzled (c^=d&7)
    short* Ph = &lds[wave * 4096 + 2048];   // [64][32] bf16, chunk-swizzled

    // ---- Q,K fragments direct from global ----
    short8 qf[4], kf[4];
    #pragma unroll
    for (int fi = 0; fi < 4; ++fi) {
        int q = fi * 16 + l15;
        long t = base + (q >> 3) * 128 + (q & 7);
        qf[fi] = *(const short8*)(Qg + (t * NHEAD + h) * 32 + g * 8);
        kf[fi] = *(const short8*)(Kg + (t * NHEAD + h) * 32 + g * 8);
    }
    if (g == 3) {
        #pragma unroll
        for (int fi = 0; fi < 4; ++fi) {
            qf[fi][6] = 0; qf[fi][7] = 0; kf[fi][6] = 0; kf[fi][7] = 0;
        }
    }

    // ---- stage V^T into LDS ----
    {
        int t = lane;
        const bf16* vp = Vg + ((base + (t >> 3) * 128 + (t & 7)) * NHEAD + h) * 32;
        short8 v0 = *(const short8*)(vp);
        short8 v1 = *(const short8*)(vp + 8);
        short8 v2 = *(const short8*)(vp + 16);
        short8 v3 = *(const short8*)(vp + 24);
        v3[6] = 0; v3[7] = 0;
        int ct = t >> 3, t7 = t & 7;
        #pragma unroll
        for (int d = 0; d < 8; ++d)  Vt[d * 64 + ((ct ^ d) << 3) + t7] = v0[d];
        #pragma unroll
        for (int d = 8; d < 16; ++d) Vt[d * 64 + ((ct ^ (d & 7)) << 3) + t7] = v1[d - 8];
        #pragma unroll
        for (int d = 16; d < 24; ++d) Vt[d * 64 + ((ct ^ (d & 7)) << 3) + t7] = v2[d - 16];
        #pragma unroll
        for (int d = 24; d < 32; ++d) Vt[d * 64 + ((ct ^ (d & 7)) << 3) + t7] = v3[d - 24];
    }

    // ---- S = bias + Q K^T ----
    f32x4 S[4][4];
    #pragma unroll
    for (int fi = 0; fi < 4; ++fi)
        #pragma unroll
        for (int fj = 0; fj < 4; ++fj)
            S[fi][fj] = *(const f32x4*)(bias_frag + (((h * 4 + fi) * 4 + fj) * 64 + lane) * 4);
    #pragma unroll
    for (int fi = 0; fi < 4; ++fi)
        #pragma unroll
        for (int fj = 0; fj < 4; ++fj)
            S[fi][fj] = __builtin_amdgcn_mfma_f32_16x16x32_bf16(qf[fi], kf[fj], S[fi][fj], 0, 0, 0);

    // ---- softmax: row max / exp / row sum ----
    f32x4 mrow[4], lsum[4];
    #pragma unroll
    for (int fi = 0; fi < 4; ++fi) {
        f32x4 a = S[fi][0], c = S[fi][2];
        #pragma unroll
        for (int cc = 0; cc < 4; ++cc) {
            a[cc] = fmaxf(a[cc], S[fi][1][cc]);
            c[cc] = fmaxf(c[cc], S[fi][3][cc]);
            a[cc] = fmaxf(a[cc], c[cc]);
        }
        mrow[fi] = a;
    }
    #pragma unroll
    for (int mask = 1; mask <= 8; mask <<= 1)
        #pragma unroll
        for (int fi = 0; fi < 4; ++fi)
            #pragma unroll
            for (int cc = 0; cc < 4; ++cc)
                mrow[fi][cc] = fmaxf(mrow[fi][cc], __shfl_xor(mrow[fi][cc], mask));
    #pragma unroll
    for (int fi = 0; fi < 4; ++fi)
        #pragma unroll
        for (int fj = 0; fj < 4; ++fj)
            #pragma unroll
            for (int cc = 0; cc < 4; ++cc)
                S[fi][fj][cc] = __expf(S[fi][fj][cc] - mrow[fi][cc]);
    #pragma unroll
    for (int fi = 0; fi < 4; ++fi) {
        f32x4 a = S[fi][0] + S[fi][1];
        f32x4 c = S[fi][2] + S[fi][3];
        lsum[fi] = a + c;
    }
    #pragma unroll
    for (int mask = 1; mask <= 8; mask <<= 1)
        #pragma unroll
        for (int fi = 0; fi < 4; ++fi)
            #pragma unroll
            for (int cc = 0; cc < 4; ++cc)
                lsum[fi][cc] += __shfl_xor(lsum[fi][cc], mask);

    // ---- PV via LDS P-half transpose ----
    f32x4 O[4][2] = {};
    #pragma unroll
    for (int ks = 0; ks < 2; ++ks) {
        // write P half (fragments fj = 2ks, 2ks+1) as bf16, swizzled
        #pragma unroll
        for (int fi = 0; fi < 4; ++fi)
            #pragma unroll
            for (int f2 = 0; f2 < 2; ++f2) {
                int fj = ks * 2 + f2;
                int kh = f2 * 16 + l15;
                #pragma unroll
                for (int r = 0; r < 4; ++r) {
                    int q = fi * 16 + g * 4 + r;
                    int c = (kh >> 3) ^ r ^ g;      // (q&3)=r, ((q>>2)&3)=g
                    Ph[q * 32 + (c << 3) + (kh & 7)] = bfbits(S[fi][fj][r]);
                }
            }
        // read V^T fragments (d-tiles) and P fragments, MFMA
        short8 vf[2];
        #pragma unroll
        for (int f2 = 0; f2 < 2; ++f2) {
            int d = f2 * 16 + l15;
            int cv = (ks * 4 + g) ^ (d & 7);
            vf[f2] = *(const short8*)&Vt[d * 64 + (cv << 3)];
        }
        #pragma unroll
        for (int fi = 0; fi < 4; ++fi) {
            int q = fi * 16 + l15;
            int cr = g ^ (q & 3) ^ ((q >> 2) & 3);
            short8 pf = *(const short8*)&Ph[q * 32 + (cr << 3)];
            #pragma unroll
            for (int f2 = 0; f2 < 2; ++f2)
                O[fi][f2] = __builtin_amdgcn_mfma_f32_16x16x32_bf16(pf, vf[f2], O[fi][f2], 0, 0, 0);
        }
    }

    // ---- store O / l, window-reverse directly ----
    #pragma unroll
    for (int fi = 0; fi < 4; ++fi) {
        f32x4 inv;
        #pragma unroll
        for (int cc = 0; cc < 4; ++cc) inv[cc] = 1.f / lsum[fi][cc];
        #pragma unroll
        for (int r = 0; r < 4; ++r) {
            int q = fi * 16 + g * 4 + r;
            long t = base + (q >> 3) * 128 + (q & 7);
            bf16* op = o + t * CPAD + h * HD;
            op[l15] = f2bf(O[fi][0][r] * inv[r]);
            if (l15 < HD - 16)
                op[16 + l15] = f2bf(O[fi][1][r] * inv[r]);
        }
    }
    // zero pad cols 180..191 (wave 0)
    if (h == 0) {
        long t = base + (lane >> 3) * 128 + (lane & 7);
        bf16* op = o + t * CPAD + C_DIM;
        short4v z4 = {0, 0, 0, 0};
        short8  z8 = {0, 0, 0, 0, 0, 0, 0, 0};
        *(short4v*)(op) = z4;
        *(short8*)(op + 4) = z8;
    }
}

// ---------------- host launch ----------------
extern "C" void kernel_launch(void* const* d_in, const int* in_sizes, int n_in,
                              void* d_out, int out_size, void* d_ws, size_t ws_size,
                              hipStream_t stream) {
    const float* x    = (const float*)d_in[0];
    const float* n1w  = (const float*)d_in[1];
    const float* n1b  = (const float*)d_in[2];
    const float* qkvw = (const float*)d_in[3];
    const float* qkvb = (const float*)d_in[4];
    const float* tbl  = (const float*)d_in[5];
    const float* pw   = (const float*)d_in[6];
    const float* pb   = (const float*)d_in[7];
    const float* n2w  = (const float*)d_in[8];
    const float* n2b  = (const float*)d_in[9];
    const float* f1w  = (const float*)d_in[10];
    const float* f1b  = (const float*)d_in[11];
    const float* f2w  = (const float*)d_in[12];
    const float* f2b  = (const float*)d_in[13];

    auto al = [](size_t b) { return (b + 255) & ~(size_t)255; };
    char* base = (char*)d_ws;
    size_t off = 0;
    auto alloc = [&](size_t bytes) -> char* { char* p = base + off; off += al(bytes); return p; };

    bf16* wq  = (bf16*)alloc((size_t)576 * 192 * 2);
    bf16* wp  = (bf16*)alloc((size_t)192 * 192 * 2);
    bf16* wf1 = (bf16*)alloc((size_t)768 * 192 * 2);
    bf16* wf2 = (bf16*)alloc((size_t)192 * 768 * 2);
    float* bfr = (float*)alloc((size_t)6144 * 4 * 4);
    size_t woff = off;

    size_t r1_per = al((size_t)IMG_TOK * HPAD * 2);   // Q/K/V [192]x3 = 576, then h[768]
    size_t r2_per = al((size_t)IMG_TOK * CPAD * 2);   // xn -> o -> x2n
    size_t r3_per = al((size_t)IMG_TOK * C_DIM * 4);  // x1 f32
    size_t per_img = r1_per + r2_per + r3_per;
    int g = 8;
    while (g > 1 && woff + per_img * (size_t)g > ws_size) g >>= 1;
    int nchunks = 8 / g;
    long Mc = (long)IMG_TOK * g;

    bf16*  R1 = (bf16*)(base + woff);
    bf16*  R2 = (bf16*)(base + woff + r1_per * g);
    float* R3 = (float*)(base + woff + (r1_per + r2_per) * g);
    long matStride = Mc * 192;          // elements per Q/K/V matrix
    bf16* Qg = R1;
    bf16* Kg = R1 + matStride;
    bf16* Vg = R1 + 2 * matStride;

    prep_w<<<(576 * 192 + 255) / 256, 256, 0, stream>>>(qkvw, wq, 180, 540, 192, 576);
    prep_w<<<(192 * 192 + 255) / 256, 256, 0, stream>>>(pw, wp, 180, 180, 192, 192);
    prep_w<<<(768 * 192 + 255) / 256, 256, 0, stream>>>(f1w, wf1, 180, 720, 192, 768);
    prep_w<<<(192 * 768 + 255) / 256, 256, 0, stream>>>(f2w, wf2, 720, 180, 768, 192);
    prep_bias<<<(6144 + 255) / 256, 256, 0, stream>>>(tbl, bfr);

    for (int ci = 0; ci < nchunks; ++ci) {
        const float* xc   = x + (size_t)ci * Mc * C_DIM;
        float*       outc = (float*)d_out + (size_t)ci * Mc * C_DIM;

        // 1. LN1 -> R2 (xn)
        ln_kernel<<<Mc / 4, 256, 0, stream>>>(xc, n1w, n1b, R2, (int)Mc);
        // 2. QKV -> Qg/Kg/Vg split, q pre-scaled
        mfma_gemm<0, 2><<<dim3(9, Mc / 128), 256, 0, stream>>>(
            R2, CPAD, wq, qkvb, 540, nullptr, 0, Qg, 0, 540, CPAD, matStride);
        // 3. MFMA window attention -> R2 (o)
        attn_mfma<<<dim3(256 * g), 384, 0, stream>>>(Qg, Kg, Vg, bfr, R2);
        // 4. proj + residual(x) -> R3 (x1, f32)
        mfma_gemm<0, 1><<<dim3(3, Mc / 128), 256, 0, stream>>>(
            R2, CPAD, wp, pb, 180, xc, 180, R3, 180, 180, CPAD, 0);
        // 5. LN2 -> R2 (x2n)
        ln_kernel<<<Mc / 4, 256, 0, stream>>>(R3, n2w, n2b, R2, (int)Mc);
        // 6. FC1 + GELU -> R1 (h)
        mfma_gemm<1, 0><<<dim3(12, Mc / 128), 256, 0, stream>>>(
            R2, CPAD, wf1, f1b, 720, nullptr, 0, R1, HPAD, HPAD, CPAD, 0);
        // 7. FC2 + residual(x1) -> out (f32)
        mfma_gemm<0, 1><<<dim3(3, Mc / 128), 256, 0, stream>>>(
            R1, HPAD, wf2, f2b, 180, R3, 180, outc, 180, 180, HPAD, 0);
    }
}